// Round 14
// baseline (336.518 us; speedup 1.0000x reference)
//
#include <hip/hip_runtime.h>
#include <hip/hip_bf16.h>

// x:[1024,3,32,32] -> conv1(3->64)+relu -> conv2(64->128)+relu -> meanpool
// -> fc(128->256)+b -> *mask -> sage1(256->256)+relu -> sage2(256->128)
// Output [32,32,128] fp32.
//
// Workspace layout (<6MB):
//  [0,2M)        pooled4 [1024][4][128] f32 (band partials, pre-divide)
//  [4096K,+256K) l1T  [256][256] = s1lw^T
//  [4352K,+256K) w1pT [256][256] = (s1rw - s1lw/31)^T
//  [4608K,+128K) l2T  [256][128] = s2lw^T
//  [4736K,+128K) w2pT [256][128] = (s2rw - s2lw/31)^T
//  [4864K,+128K) fwT  [128][256] = fc_w^T
//  [4992K,+144K) w2b  [9][128][64] bf16 conv2 w, tap-major
//  [5136K,+4K)   w1b  [64][32] bf16 conv1 w+bias (k=27 slot = bias)

typedef __attribute__((ext_vector_type(8))) short bfrag;
typedef __attribute__((ext_vector_type(4))) float f32x4;

static __device__ __forceinline__ unsigned short f2bf(float f) {
    union { float f; unsigned u; } v; v.f = f;
    unsigned r = v.u + 0x7fff + ((v.u >> 16) & 1);   // RNE (finite)
    return (unsigned short)(r >> 16);
}

__global__ __launch_bounds__(256) void prep_kernel(
    const float* __restrict__ s1lw, const float* __restrict__ s1rw,
    const float* __restrict__ s2lw, const float* __restrict__ s2rw,
    const float* __restrict__ c2w, const float* __restrict__ c1w,
    const float* __restrict__ c1b, const float* __restrict__ fcw,
    float* __restrict__ l1T, float* __restrict__ w1pT,
    float* __restrict__ l2T, float* __restrict__ w2pT,
    float* __restrict__ fwT,
    short* __restrict__ w2b, short* __restrict__ w1b) {
    int i = blockIdx.x * 256 + threadIdx.x;     // grid 288 -> [0, 73728)
    const float inv31 = 1.f / 31.f;
    if (i < 65536) {
        int d = i >> 8, o = i & 255;
        float lw = s1lw[o * 256 + d];
        l1T[i]  = lw;
        w1pT[i] = s1rw[o * 256 + d] - lw * inv31;
    }
    if (i < 32768) {
        int d = i >> 7, o = i & 127;
        float lw = s2lw[o * 256 + d];
        l2T[i]  = lw;
        w2pT[i] = s2rw[o * 256 + d] - lw * inv31;
        int c = i >> 8, o2 = i & 255;
        fwT[i] = fcw[o2 * 128 + c];
    }
    if (i < 73728) {                            // w2b[k][oc][ic] = c2w[oc][ic][k]
        int k = i >> 13, rem = i & 8191, oc = rem >> 6, ic = rem & 63;
        w2b[i] = (short)f2bf(c2w[(oc * 64 + ic) * 9 + k]);
    }
    if (i < 2048) {                             // w1b[oc][k], k=27 -> bias
        int oc = i >> 5, k = i & 31;
        float v = (k < 27) ? c1w[oc * 27 + k] : (k == 27 ? c1b[oc] : 0.f);
        w1b[i] = (short)f2bf(v);
    }
}

// Fused conv1+conv2+pool: grid (4 bands of 8 rows, 1024 imgs). Measured local
// optimum (r7-r13): wave = 128 pos x 64 oc, acc=128 AGPR, 2-stage B pipeline,
// (256,2) only (r8: tighter bound spills acc; r10: smaller tiles lose).
__global__ __launch_bounds__(256, 2) void fused_conv_kernel(
    const float* __restrict__ x, const short* __restrict__ w1b,
    const short* __restrict__ w2b, const float* __restrict__ b2,
    float* __restrict__ pooled4) {
    const int band = blockIdx.x, img = blockIdx.y;
    __shared__ short xt[3 * 12 * 34];     // 2448 B: input rows band*8-2..band*8+9
    __shared__ short c1t[10 * 34 * 72];   // 48960 B [row][col pad34][ic pad72]
    __shared__ float wsum[4][64];
    const int t = threadIdx.x;
    const int w = t >> 6, lane = t & 63;
    const int ln15 = lane & 15, q8 = (lane >> 4) * 8;
    const int rg2 = w & 1, og = w >> 1;   // phase-B row-group / oc-group

    const float* xi = x + img * 3072;
    for (int idx = t; idx < 1224; idx += 256) {
        int c = idx / 408, rem = idx % 408, r = rem / 34, col = rem % 34;
        int y = band * 8 - 2 + r, xx = col - 1;
        float v = 0.f;
        if ((unsigned)y < 32u && (unsigned)xx < 32u) v = xi[c * 1024 + y * 32 + xx];
        xt[idx] = (short)f2bf(v);
    }
    {
        f32x4 z = {0.f, 0.f, 0.f, 0.f};
        for (int i = t; i < 180; i += 256) {          // 10r x 2c x 9 f32x4
            int r = i / 18, rem = i % 18, side = rem / 9, q = rem % 9;
            *(f32x4*)(c1t + (r * 34 + side * 33) * 72 + q * 8) = z;
        }
    }
    bfrag b1f[4];
#pragma unroll
    for (int ot = 0; ot < 4; ++ot)
        b1f[ot] = *(const bfrag*)(w1b + (ot * 16 + ln15) * 32 + q8);
    __syncthreads();

    // ---- phase A: conv1 -> c1t (20 pos-tiles; wave w -> tiles 5w..5w+4) ----
#pragma unroll 1
    for (int pt = 0; pt < 5; ++pt) {
        const int tile = w * 5 + pt;
        const int posA = tile * 16 + ln15;
        const int baseA = (posA >> 5) * 34 + (posA & 31);
        bfrag a1f;
#pragma unroll
        for (int j = 0; j < 8; ++j) {
            int k = q8 + j;
            int c = (k * 57) >> 9;               // k/9 for k<36
            int rem = k - 9 * c;
            int dy = (rem * 11) >> 5;            // rem/3 for rem<9
            int dx = rem - 3 * dy;
            int cc = c < 3 ? c : 2;
            short v = xt[cc * 408 + baseA + dy * 34 + dx];
            if (c >= 3) v = (k == 27) ? (short)0x3F80 : (short)0;
            a1f[j] = v;
        }
        f32x4 acc1[4];
#pragma unroll
        for (int ot = 0; ot < 4; ++ot) {
#pragma unroll
            for (int rg = 0; rg < 4; ++rg) acc1[ot][rg] = 0.f;
            acc1[ot] = __builtin_amdgcn_mfma_f32_16x16x32_bf16(
                a1f, b1f[ot], acc1[ot], 0, 0, 0);
        }
#pragma unroll
        for (int rg = 0; rg < 4; ++rg) {
            int pos = tile * 16 + (lane >> 4) * 4 + rg;  // 0..319
            int r = pos >> 5, xc = pos & 31;
            int y = band * 8 - 1 + r;
            bool valid = (unsigned)y < 32u;
#pragma unroll
            for (int ot = 0; ot < 4; ++ot) {
                float v = fmaxf(acc1[ot][rg], 0.f);
                c1t[(r * 34 + xc + 1) * 72 + ot * 16 + ln15] =
                    valid ? (short)f2bf(v) : (short)0;
            }
        }
    }
    __syncthreads();

    // ---- phase B: pipelined conv2 ----
    float b2v[4];
#pragma unroll
    for (int ot = 0; ot < 4; ++ot) b2v[ot] = b2[og * 64 + ot * 16 + ln15];

    f32x4 acc[8][4];
#pragma unroll
    for (int pt = 0; pt < 8; ++pt)
#pragma unroll
        for (int ot = 0; ot < 4; ++ot)
#pragma unroll
            for (int rg = 0; rg < 4; ++rg) acc[pt][ot][rg] = 0.f;

    int aBase[8];
#pragma unroll
    for (int pt = 0; pt < 8; ++pt) {
        int r = rg2 * 4 + (pt >> 1);
        int xc = ((pt & 1) << 4) + ln15;
        aBase[pt] = (r * 34 + xc) * 72 + q8;
    }

    const short* wb0 = w2b + (og * 64 + ln15) * 64 + q8;
    auto loadB = [&](bfrag* dst, int tap) {
        const short* p = wb0 + tap * 8192;
#pragma unroll
        for (int kc = 0; kc < 2; ++kc)
#pragma unroll
            for (int ot = 0; ot < 4; ++ot)
                dst[kc * 4 + ot] = *(const bfrag*)(p + ot * 1024 + kc * 32);
    };
    auto compute = [&](const bfrag* bf, int tap) {
        const int dy = tap / 3, dx = tap - dy * 3;
        const int dOff = (dy * 34 + dx) * 72;          // wave-uniform -> SALU
#pragma unroll
        for (int pt = 0; pt < 8; ++pt) {
            const int a0 = aBase[pt] + dOff;
#pragma unroll
            for (int kc = 0; kc < 2; ++kc) {
                bfrag a2f = *(const bfrag*)(&c1t[a0 + kc * 32]);
#pragma unroll
                for (int ot = 0; ot < 4; ++ot)
                    acc[pt][ot] = __builtin_amdgcn_mfma_f32_16x16x32_bf16(
                        a2f, bf[kc * 4 + ot], acc[pt][ot], 0, 0, 0);
            }
        }
    };

    bfrag bA[8], bB[8];
    loadB(bA, 0);
#pragma unroll 1
    for (int tap = 0; tap < 9; tap += 2) {      // manual 2-stage pipeline
        if (tap + 1 < 9) loadB(bB, tap + 1);
        compute(bA, tap);
        if (tap + 2 < 9) loadB(bA, tap + 2);
        if (tap + 1 < 9) compute(bB, tap + 1);
    }

#pragma unroll
    for (int ot = 0; ot < 4; ++ot) {
        float s = 0.f;
#pragma unroll
        for (int pt = 0; pt < 8; ++pt)
#pragma unroll
            for (int rg = 0; rg < 4; ++rg)
                s += fmaxf(acc[pt][ot][rg] + b2v[ot], 0.f);
        s += __shfl_xor(s, 16, 64);
        s += __shfl_xor(s, 32, 64);
        if (lane < 16) wsum[w][ot * 16 + ln15] = s;
    }
    __syncthreads();
    if (t < 128) {
        int og2 = t >> 6, oo = t & 63;
        pooled4[((size_t)img * 4 + band) * 128 + t] =
            wsum[og2 * 2][oo] + wsum[og2 * 2 + 1][oo];
    }
}

// Merged tail: fc + mask + sage1 + relu + sage2, grid 256 = (batch, 8 chunks).
// Each block REDUNDANTLY computes fc+sage1 for all 32 nodes (needed for the
// means anyway; ~27K cyc, fully parallel at 1 block/CU), then sage2 for its
// 4-node chunk. Kills 2 launches + z1/z2 HBM round-trips. r6 lesson: the old
// merged tail failed at grid 32 (1/8 chip); 256 blocks = 1/CU fixes that.
__global__ __launch_bounds__(256) void tail_kernel(
    const float* __restrict__ pooled4, const float* __restrict__ fwT,
    const float* __restrict__ fb, const float* __restrict__ mask,
    const float* __restrict__ l1T, const float* __restrict__ lb1,
    const float* __restrict__ w1pT, const float* __restrict__ l2T,
    const float* __restrict__ lb2, const float* __restrict__ w2pT,
    float* __restrict__ out) {
    const int bb = blockIdx.x >> 3, chunk = blockIdx.x & 7;
    __shared__ float m[32 * 128];
    __shared__ float hA[32 * 256];
    __shared__ float hB[32 * 256];
    __shared__ float sl[256];
    __shared__ float mk[32];
    const int t = threadIdx.x;
    if (t < 32) mk[t] = mask[bb * 32 + t];
    for (int idx = t; idx < 4096; idx += 256) {
        int n = idx >> 7, c = idx & 127;
        const float* p = pooled4 + ((size_t)(bb * 32 + n) * 4) * 128 + c;
        m[idx] = (p[0] + p[128] + p[256] + p[384]) * (1.f / 1024.f);
    }
    __syncthreads();
    // fc for all 32 nodes; thread t = output dim
    float acc[32];
#pragma unroll
    for (int n = 0; n < 32; ++n) acc[n] = 0.f;
    for (int c0 = 0; c0 < 128; c0 += 4) {
        float wv0 = fwT[(c0 + 0) * 256 + t];
        float wv1 = fwT[(c0 + 1) * 256 + t];
        float wv2 = fwT[(c0 + 2) * 256 + t];
        float wv3 = fwT[(c0 + 3) * 256 + t];
#pragma unroll
        for (int n = 0; n < 32; ++n) {
            f32x4 hv = *(const f32x4*)&m[n * 128 + c0];
            acc[n] = fmaf(hv[0], wv0, acc[n]);
            acc[n] = fmaf(hv[1], wv1, acc[n]);
            acc[n] = fmaf(hv[2], wv2, acc[n]);
            acc[n] = fmaf(hv[3], wv3, acc[n]);
        }
    }
    {
        float fbv = fb[t];
        for (int n = 0; n < 32; ++n) hA[n * 256 + t] = (acc[n] + fbv) * mk[n];
    }
    __syncthreads();
    {
        float s = 0.f;
#pragma unroll
        for (int n = 0; n < 32; ++n) s += hA[n * 256 + t];
        sl[t] = s * (1.f / 31.f);
    }
    __syncthreads();
    // sage1 for all 32 nodes
    {
        float c1v = lb1[t];
#pragma unroll 4
        for (int d = 0; d < 256; ++d) c1v = fmaf(sl[d], l1T[d * 256 + t], c1v);
#pragma unroll
        for (int n = 0; n < 32; ++n) acc[n] = c1v;
        for (int d0 = 0; d0 < 256; d0 += 4) {
            float wv0 = w1pT[(d0 + 0) * 256 + t];
            float wv1 = w1pT[(d0 + 1) * 256 + t];
            float wv2 = w1pT[(d0 + 2) * 256 + t];
            float wv3 = w1pT[(d0 + 3) * 256 + t];
#pragma unroll
            for (int n = 0; n < 32; ++n) {
                f32x4 hv = *(const f32x4*)&hA[n * 256 + d0];
                acc[n] = fmaf(hv[0], wv0, acc[n]);
                acc[n] = fmaf(hv[1], wv1, acc[n]);
                acc[n] = fmaf(hv[2], wv2, acc[n]);
                acc[n] = fmaf(hv[3], wv3, acc[n]);
            }
        }
        for (int n = 0; n < 32; ++n) hB[n * 256 + t] = fmaxf(acc[n], 0.f);
    }
    __syncthreads();
    {
        float s = 0.f;
#pragma unroll
        for (int n = 0; n < 32; ++n) s += hB[n * 256 + t];
        sl[t] = s * (1.f / 31.f);
    }
    __syncthreads();
    // sage2 for this block's 4 nodes: o = t&127, half = t>>7 (2 nodes each)
    {
        const int o = t & 127, half = t >> 7;
        float c2v = lb2[o];
#pragma unroll 4
        for (int d = 0; d < 256; ++d) c2v = fmaf(sl[d], l2T[d * 128 + o], c2v);
        float a2[2];
        a2[0] = c2v; a2[1] = c2v;
        const int n0 = chunk * 4 + half * 2;
        for (int d0 = 0; d0 < 256; d0 += 4) {
            float wv0 = w2pT[(d0 + 0) * 128 + o];
            float wv1 = w2pT[(d0 + 1) * 128 + o];
            float wv2 = w2pT[(d0 + 2) * 128 + o];
            float wv3 = w2pT[(d0 + 3) * 128 + o];
#pragma unroll
            for (int ii = 0; ii < 2; ++ii) {
                f32x4 hv = *(const f32x4*)&hB[(n0 + ii) * 256 + d0];
                a2[ii] = fmaf(hv[0], wv0, a2[ii]);
                a2[ii] = fmaf(hv[1], wv1, a2[ii]);
                a2[ii] = fmaf(hv[2], wv2, a2[ii]);
                a2[ii] = fmaf(hv[3], wv3, a2[ii]);
            }
        }
        for (int ii = 0; ii < 2; ++ii)
            out[(size_t)(bb * 32 + n0 + ii) * 128 + o] = a2[ii];
    }
}

extern "C" void kernel_launch(void* const* d_in, const int* in_sizes, int n_in,
                              void* d_out, int out_size, void* d_ws, size_t ws_size,
                              hipStream_t stream) {
    const float* x    = (const float*)d_in[0];
    const float* mask = (const float*)d_in[1];
    const float* c1w  = (const float*)d_in[2];
    const float* c1b  = (const float*)d_in[3];
    const float* c2w  = (const float*)d_in[4];
    const float* c2b  = (const float*)d_in[5];
    const float* fcw  = (const float*)d_in[6];
    const float* fcb  = (const float*)d_in[7];
    const float* s1lw = (const float*)d_in[8];
    const float* s1lb = (const float*)d_in[9];
    const float* s1rw = (const float*)d_in[10];
    const float* s2lw = (const float*)d_in[11];
    const float* s2lb = (const float*)d_in[12];
    const float* s2rw = (const float*)d_in[13];
    float* out = (float*)d_out;

    char* ws = (char*)d_ws;
    float* pooled4 = (float*)(ws);
    float* l1T     = (float*)(ws + 4096u * 1024);
    float* w1pT    = (float*)(ws + 4352u * 1024);
    float* l2T     = (float*)(ws + 4608u * 1024);
    float* w2pT    = (float*)(ws + 4736u * 1024);
    float* fwT     = (float*)(ws + 4864u * 1024);
    short* w2b     = (short*)(ws + 4992u * 1024);
    short* w1b     = (short*)(ws + 5136u * 1024);

    prep_kernel<<<dim3(288), 256, 0, stream>>>(s1lw, s1rw, s2lw, s2rw, c2w, c1w, c1b,
                                               fcw, l1T, w1pT, l2T, w2pT, fwT, w2b, w1b);
    fused_conv_kernel<<<dim3(4, 1024), 256, 0, stream>>>(x, w1b, w2b, c2b, pooled4);
    tail_kernel<<<dim3(256), 256, 0, stream>>>(pooled4, fwT, fcb, mask,
                                               l1T, s1lb, w1pT, l2T, s2lb, w2pT, out);
}

// Round 15
// 314.208 us; speedup vs baseline: 1.0710x; 1.0710x over previous
//
#include <hip/hip_runtime.h>
#include <hip/hip_bf16.h>

// x:[1024,3,32,32] -> conv1(3->64)+relu -> conv2(64->128)+relu -> meanpool
// -> fc(128->256)+b -> *mask -> sage1(256->256)+relu -> sage2(256->128)
// Output [32,32,128] fp32.
//
// Workspace layout (<6MB):
//  [0,2M)        pooled4 [1024][4][128] f32 (band partials, pre-divide)
//  [2M,3M)       z1 [1024][256]
//  [3M,4M)       z2 [1024][256]
//  [4096K,+256K) l1T  [256][256] = s1lw^T
//  [4352K,+256K) w1pT [256][256] = (s1rw - s1lw/31)^T
//  [4608K,+128K) l2T  [256][128] = s2lw^T
//  [4736K,+128K) w2pT [256][128] = (s2rw - s2lw/31)^T
//  [4864K,+128K) fwT  [128][256] = fc_w^T
//  [4992K,+144K) w2b  [9][128][64] bf16 conv2 w, tap-major
//  [5136K,+4K)   w1b  [64][32] bf16 conv1 w+bias (k=27 slot = bias)

typedef __attribute__((ext_vector_type(8))) short bfrag;
typedef __attribute__((ext_vector_type(4))) float f32x4;

static __device__ __forceinline__ unsigned short f2bf(float f) {
    union { float f; unsigned u; } v; v.f = f;
    unsigned r = v.u + 0x7fff + ((v.u >> 16) & 1);   // RNE (finite)
    return (unsigned short)(r >> 16);
}

// prep: grid 64. Blocks 0-15: 256x256 transpose pair (s1lw/s1rw -> l1T/w1pT);
// 16-23: 128x256 pair (s2lw/s2rw -> l2T/w2pT); 24-31: fcw -> fwT; 32-63: w2b
// repack (+w1b in block 32). LDS 64x65 tiles: coalesced both directions
// (r13's raw transposes gathered 64 cache lines/wave -> ~20us; this is ~5us).
__global__ __launch_bounds__(256) void prep_kernel(
    const float* __restrict__ s1lw, const float* __restrict__ s1rw,
    const float* __restrict__ s2lw, const float* __restrict__ s2rw,
    const float* __restrict__ c2w, const float* __restrict__ c1w,
    const float* __restrict__ c1b, const float* __restrict__ fcw,
    float* __restrict__ l1T, float* __restrict__ w1pT,
    float* __restrict__ l2T, float* __restrict__ w2pT,
    float* __restrict__ fwT,
    short* __restrict__ w2b, short* __restrict__ w1b) {
    const int blk = blockIdx.x, t = threadIdx.x;
    const int rr = t >> 6, cc = t & 63;
    const float inv31 = 1.f / 31.f;
    __shared__ float tA[64][65];
    __shared__ float tB[64][65];
    if (blk < 16) {                       // 256x256: [o][d] -> [d][o]
        int br = (blk >> 2) * 64, bc = (blk & 3) * 64;
#pragma unroll
        for (int i = 0; i < 16; ++i) {
            int o = br + i * 4 + rr;
            tA[i * 4 + rr][cc] = s1lw[o * 256 + bc + cc];
            tB[i * 4 + rr][cc] = s1rw[o * 256 + bc + cc];
        }
        __syncthreads();
#pragma unroll
        for (int i = 0; i < 16; ++i) {
            int d = bc + i * 4 + rr;
            float lw = tA[cc][i * 4 + rr];
            float rw = tB[cc][i * 4 + rr];
            l1T[d * 256 + br + cc]  = lw;
            w1pT[d * 256 + br + cc] = rw - lw * inv31;
        }
    } else if (blk < 24) {                // 128x256: [o][d] -> [d][o] (256x128)
        int b = blk - 16;
        int br = (b >> 2) * 64, bc = (b & 3) * 64;   // o0, d0
#pragma unroll
        for (int i = 0; i < 16; ++i) {
            int o = br + i * 4 + rr;
            tA[i * 4 + rr][cc] = s2lw[o * 256 + bc + cc];
            tB[i * 4 + rr][cc] = s2rw[o * 256 + bc + cc];
        }
        __syncthreads();
#pragma unroll
        for (int i = 0; i < 16; ++i) {
            int d = bc + i * 4 + rr;
            float lw = tA[cc][i * 4 + rr];
            float rw = tB[cc][i * 4 + rr];
            l2T[d * 128 + br + cc]  = lw;
            w2pT[d * 128 + br + cc] = rw - lw * inv31;
        }
    } else if (blk < 32) {                // fcw [o 256][c 128] -> fwT [c][o]
        int b = blk - 24;
        int br = (b >> 1) * 64, bc = (b & 1) * 64;   // o0, c0
#pragma unroll
        for (int i = 0; i < 16; ++i) {
            int o = br + i * 4 + rr;
            tA[i * 4 + rr][cc] = fcw[o * 128 + bc + cc];
        }
        __syncthreads();
#pragma unroll
        for (int i = 0; i < 16; ++i) {
            int c = bc + i * 4 + rr;
            fwT[c * 256 + br + cc] = tA[cc][i * 4 + rr];
        }
    } else {                              // w2b[k][oc][ic] = c2w[oc][ic][k]
        int base = (blk - 32) * 2304 + t;
#pragma unroll
        for (int j = 0; j < 9; ++j) {
            int i = base + j * 256;
            int k = i >> 13, rem = i & 8191, oc = rem >> 6, ic = rem & 63;
            w2b[i] = (short)f2bf(c2w[(oc * 64 + ic) * 9 + k]);
        }
        if (blk == 32) {                  // w1b[oc][k], k=27 -> bias
            for (int j = t; j < 2048; j += 256) {
                int oc = j >> 5, k = j & 31;
                float v = (k < 27) ? c1w[oc * 27 + k] : (k == 27 ? c1b[oc] : 0.f);
                w1b[j] = (short)f2bf(v);
            }
        }
    }
}

// Fused conv1+conv2+pool: grid (4 bands of 8 rows, 1024 imgs). Measured local
// optimum (r7-r13): wave = 128 pos x 64 oc, acc=128 AGPR, 2-stage B pipeline,
// (256,2) only (r8: tighter bound spills acc; r10: smaller tiles lose).
__global__ __launch_bounds__(256, 2) void fused_conv_kernel(
    const float* __restrict__ x, const short* __restrict__ w1b,
    const short* __restrict__ w2b, const float* __restrict__ b2,
    float* __restrict__ pooled4) {
    const int band = blockIdx.x, img = blockIdx.y;
    __shared__ short xt[3 * 12 * 34];     // 2448 B: input rows band*8-2..band*8+9
    __shared__ short c1t[10 * 34 * 72];   // 48960 B [row][col pad34][ic pad72]
    __shared__ float wsum[4][64];
    const int t = threadIdx.x;
    const int w = t >> 6, lane = t & 63;
    const int ln15 = lane & 15, q8 = (lane >> 4) * 8;
    const int rg2 = w & 1, og = w >> 1;   // phase-B row-group / oc-group

    const float* xi = x + img * 3072;
    for (int idx = t; idx < 1224; idx += 256) {
        int c = idx / 408, rem = idx % 408, r = rem / 34, col = rem % 34;
        int y = band * 8 - 2 + r, xx = col - 1;
        float v = 0.f;
        if ((unsigned)y < 32u && (unsigned)xx < 32u) v = xi[c * 1024 + y * 32 + xx];
        xt[idx] = (short)f2bf(v);
    }
    {
        f32x4 z = {0.f, 0.f, 0.f, 0.f};
        for (int i = t; i < 180; i += 256) {          // 10r x 2c x 9 f32x4
            int r = i / 18, rem = i % 18, side = rem / 9, q = rem % 9;
            *(f32x4*)(c1t + (r * 34 + side * 33) * 72 + q * 8) = z;
        }
    }
    bfrag b1f[4];
#pragma unroll
    for (int ot = 0; ot < 4; ++ot)
        b1f[ot] = *(const bfrag*)(w1b + (ot * 16 + ln15) * 32 + q8);
    __syncthreads();

    // ---- phase A: conv1 -> c1t (20 pos-tiles; wave w -> tiles 5w..5w+4) ----
#pragma unroll 1
    for (int pt = 0; pt < 5; ++pt) {
        const int tile = w * 5 + pt;
        const int posA = tile * 16 + ln15;
        const int baseA = (posA >> 5) * 34 + (posA & 31);
        bfrag a1f;
#pragma unroll
        for (int j = 0; j < 8; ++j) {
            int k = q8 + j;
            int c = (k * 57) >> 9;               // k/9 for k<36
            int rem = k - 9 * c;
            int dy = (rem * 11) >> 5;            // rem/3 for rem<9
            int dx = rem - 3 * dy;
            int cc = c < 3 ? c : 2;
            short v = xt[cc * 408 + baseA + dy * 34 + dx];
            if (c >= 3) v = (k == 27) ? (short)0x3F80 : (short)0;
            a1f[j] = v;
        }
        f32x4 acc1[4];
#pragma unroll
        for (int ot = 0; ot < 4; ++ot) {
#pragma unroll
            for (int rg = 0; rg < 4; ++rg) acc1[ot][rg] = 0.f;
            acc1[ot] = __builtin_amdgcn_mfma_f32_16x16x32_bf16(
                a1f, b1f[ot], acc1[ot], 0, 0, 0);
        }
#pragma unroll
        for (int rg = 0; rg < 4; ++rg) {
            int pos = tile * 16 + (lane >> 4) * 4 + rg;  // 0..319
            int r = pos >> 5, xc = pos & 31;
            int y = band * 8 - 1 + r;
            bool valid = (unsigned)y < 32u;
#pragma unroll
            for (int ot = 0; ot < 4; ++ot) {
                float v = fmaxf(acc1[ot][rg], 0.f);
                c1t[(r * 34 + xc + 1) * 72 + ot * 16 + ln15] =
                    valid ? (short)f2bf(v) : (short)0;
            }
        }
    }
    __syncthreads();

    // ---- phase B: pipelined conv2 ----
    float b2v[4];
#pragma unroll
    for (int ot = 0; ot < 4; ++ot) b2v[ot] = b2[og * 64 + ot * 16 + ln15];

    f32x4 acc[8][4];
#pragma unroll
    for (int pt = 0; pt < 8; ++pt)
#pragma unroll
        for (int ot = 0; ot < 4; ++ot)
#pragma unroll
            for (int rg = 0; rg < 4; ++rg) acc[pt][ot][rg] = 0.f;

    int aBase[8];
#pragma unroll
    for (int pt = 0; pt < 8; ++pt) {
        int r = rg2 * 4 + (pt >> 1);
        int xc = ((pt & 1) << 4) + ln15;
        aBase[pt] = (r * 34 + xc) * 72 + q8;
    }

    const short* wb0 = w2b + (og * 64 + ln15) * 64 + q8;
    auto loadB = [&](bfrag* dst, int tap) {
        const short* p = wb0 + tap * 8192;
#pragma unroll
        for (int kc = 0; kc < 2; ++kc)
#pragma unroll
            for (int ot = 0; ot < 4; ++ot)
                dst[kc * 4 + ot] = *(const bfrag*)(p + ot * 1024 + kc * 32);
    };
    auto compute = [&](const bfrag* bf, int tap) {
        const int dy = tap / 3, dx = tap - dy * 3;
        const int dOff = (dy * 34 + dx) * 72;          // wave-uniform -> SALU
#pragma unroll
        for (int pt = 0; pt < 8; ++pt) {
            const int a0 = aBase[pt] + dOff;
#pragma unroll
            for (int kc = 0; kc < 2; ++kc) {
                bfrag a2f = *(const bfrag*)(&c1t[a0 + kc * 32]);
#pragma unroll
                for (int ot = 0; ot < 4; ++ot)
                    acc[pt][ot] = __builtin_amdgcn_mfma_f32_16x16x32_bf16(
                        a2f, bf[kc * 4 + ot], acc[pt][ot], 0, 0, 0);
            }
        }
    };

    bfrag bA[8], bB[8];
    loadB(bA, 0);
#pragma unroll 1
    for (int tap = 0; tap < 9; tap += 2) {      // manual 2-stage pipeline
        if (tap + 1 < 9) loadB(bB, tap + 1);
        compute(bA, tap);
        if (tap + 2 < 9) loadB(bA, tap + 2);
        if (tap + 1 < 9) compute(bB, tap + 1);
    }

#pragma unroll
    for (int ot = 0; ot < 4; ++ot) {
        float s = 0.f;
#pragma unroll
        for (int pt = 0; pt < 8; ++pt)
#pragma unroll
            for (int rg = 0; rg < 4; ++rg)
                s += fmaxf(acc[pt][ot][rg] + b2v[ot], 0.f);
        s += __shfl_xor(s, 16, 64);
        s += __shfl_xor(s, 32, 64);
        if (lane < 16) wsum[w][ot * 16 + ln15] = s;
    }
    __syncthreads();
    if (t < 128) {
        int og2 = t >> 6, oo = t & 63;
        pooled4[((size_t)img * 4 + band) * 128 + t] =
            wsum[og2 * 2][oo] + wsum[og2 * 2 + 1][oo];
    }
}

// fc: grid 1024 (one block per image) -- wide grid hides weight-load latency.
__global__ __launch_bounds__(256) void fc_kernel(
    const float* __restrict__ pooled4, const float* __restrict__ fwT,
    const float* __restrict__ fb, const float* __restrict__ mask,
    float* __restrict__ z1) {
    const int img = blockIdx.x;
    __shared__ float m[128];
    const int t = threadIdx.x;
    if (t < 128) {
        const float* p = pooled4 + (size_t)img * 4 * 128 + t;
        m[t] = (p[0] + p[128] + p[256] + p[384]) * (1.f / 1024.f);
    }
    __syncthreads();
    float acc = fb[t];
#pragma unroll 4
    for (int c = 0; c < 128; ++c) acc = fmaf(m[c], fwT[c * 256 + t], acc);  // coalesced
    z1[img * 256 + t] = acc * mask[img];
}

// sage1+relu: grid 256 = (bb, chunk of 4 nodes); thread t = output o.
__global__ __launch_bounds__(256) void sage1_kernel(
    const float* __restrict__ z1, const float* __restrict__ l1T,
    const float* __restrict__ lb, const float* __restrict__ w1pT,
    float* __restrict__ z2) {
    const int bb = blockIdx.x >> 3, chunk = blockIdx.x & 7;
    __shared__ float h[32 * 256];
    __shared__ float sl[256];
    const int t = threadIdx.x;
    const float* zb = z1 + bb * 8192;
    for (int idx = t; idx < 8192; idx += 256) h[idx] = zb[idx];
    __syncthreads();
    float s = 0.f;
#pragma unroll
    for (int n = 0; n < 32; ++n) s += h[n * 256 + t];
    sl[t] = s * (1.f / 31.f);
    __syncthreads();
    float c = lb[t];
#pragma unroll 4
    for (int d = 0; d < 256; ++d) c = fmaf(sl[d], l1T[d * 256 + t], c);
    float acc[4];
#pragma unroll
    for (int i = 0; i < 4; ++i) acc[i] = c;
    for (int d0 = 0; d0 < 256; d0 += 4) {
        float wv0 = w1pT[(d0 + 0) * 256 + t];
        float wv1 = w1pT[(d0 + 1) * 256 + t];
        float wv2 = w1pT[(d0 + 2) * 256 + t];
        float wv3 = w1pT[(d0 + 3) * 256 + t];
#pragma unroll
        for (int i = 0; i < 4; ++i) {
            f32x4 hv = *(const f32x4*)&h[(chunk * 4 + i) * 256 + d0];  // LDS broadcast
            acc[i] = fmaf(hv[0], wv0, acc[i]);
            acc[i] = fmaf(hv[1], wv1, acc[i]);
            acc[i] = fmaf(hv[2], wv2, acc[i]);
            acc[i] = fmaf(hv[3], wv3, acc[i]);
        }
    }
    for (int i = 0; i < 4; ++i)
        z2[(bb * 32 + chunk * 4 + i) * 256 + t] = fmaxf(acc[i], 0.f);
}

// sage2: grid 256 = (bb, chunk of 4 nodes); o = t&127, half = t>>7 (2 nodes each).
__global__ __launch_bounds__(256) void sage2_kernel(
    const float* __restrict__ z2, const float* __restrict__ l2T,
    const float* __restrict__ lb, const float* __restrict__ w2pT,
    float* __restrict__ out) {
    const int bb = blockIdx.x >> 3, chunk = blockIdx.x & 7;
    __shared__ float h[32 * 256];
    __shared__ float sl[256];
    const int t = threadIdx.x;
    const float* zb = z2 + bb * 8192;
    for (int idx = t; idx < 8192; idx += 256) h[idx] = zb[idx];
    __syncthreads();
    float s = 0.f;
#pragma unroll
    for (int n = 0; n < 32; ++n) s += h[n * 256 + t];
    sl[t] = s * (1.f / 31.f);
    __syncthreads();
    const int o = t & 127, half = t >> 7;
    float c = lb[o];
#pragma unroll 4
    for (int d = 0; d < 256; ++d) c = fmaf(sl[d], l2T[d * 128 + o], c);
    float acc[2];
    acc[0] = c; acc[1] = c;
    const int n0 = chunk * 4 + half * 2;
    for (int d0 = 0; d0 < 256; d0 += 4) {
        float wv0 = w2pT[(d0 + 0) * 128 + o];
        float wv1 = w2pT[(d0 + 1) * 128 + o];
        float wv2 = w2pT[(d0 + 2) * 128 + o];
        float wv3 = w2pT[(d0 + 3) * 128 + o];
#pragma unroll
        for (int ii = 0; ii < 2; ++ii) {
            f32x4 hv = *(const f32x4*)&h[(n0 + ii) * 256 + d0];
            acc[ii] = fmaf(hv[0], wv0, acc[ii]);
            acc[ii] = fmaf(hv[1], wv1, acc[ii]);
            acc[ii] = fmaf(hv[2], wv2, acc[ii]);
            acc[ii] = fmaf(hv[3], wv3, acc[ii]);
        }
    }
    for (int ii = 0; ii < 2; ++ii)
        out[(size_t)(bb * 32 + n0 + ii) * 128 + o] = acc[ii];
}

extern "C" void kernel_launch(void* const* d_in, const int* in_sizes, int n_in,
                              void* d_out, int out_size, void* d_ws, size_t ws_size,
                              hipStream_t stream) {
    const float* x    = (const float*)d_in[0];
    const float* mask = (const float*)d_in[1];
    const float* c1w  = (const float*)d_in[2];
    const float* c1b  = (const float*)d_in[3];
    const float* c2w  = (const float*)d_in[4];
    const float* c2b  = (const float*)d_in[5];
    const float* fcw  = (const float*)d_in[6];
    const float* fcb  = (const float*)d_in[7];
    const float* s1lw = (const float*)d_in[8];
    const float* s1lb = (const float*)d_in[9];
    const float* s1rw = (const float*)d_in[10];
    const float* s2lw = (const float*)d_in[11];
    const float* s2lb = (const float*)d_in[12];
    const float* s2rw = (const float*)d_in[13];
    float* out = (float*)d_out;

    char* ws = (char*)d_ws;
    float* pooled4 = (float*)(ws);
    float* z1      = (float*)(ws + 2048u * 1024);
    float* z2      = (float*)(ws + 3072u * 1024);
    float* l1T     = (float*)(ws + 4096u * 1024);
    float* w1pT    = (float*)(ws + 4352u * 1024);
    float* l2T     = (float*)(ws + 4608u * 1024);
    float* w2pT    = (float*)(ws + 4736u * 1024);
    float* fwT     = (float*)(ws + 4864u * 1024);
    short* w2b     = (short*)(ws + 4992u * 1024);
    short* w1b     = (short*)(ws + 5136u * 1024);

    prep_kernel<<<dim3(64), 256, 0, stream>>>(s1lw, s1rw, s2lw, s2rw, c2w, c1w, c1b,
                                              fcw, l1T, w1pT, l2T, w2pT, fwT, w2b, w1b);
    fused_conv_kernel<<<dim3(4, 1024), 256, 0, stream>>>(x, w1b, w2b, c2b, pooled4);
    fc_kernel<<<dim3(1024), 256, 0, stream>>>(pooled4, fwT, fcb, mask, z1);
    sage1_kernel<<<dim3(256), 256, 0, stream>>>(z1, l1T, s1lb, w1pT, z2);
    sage2_kernel<<<dim3(256), 256, 0, stream>>>(z2, l2T, s2lb, w2pT, out);
}

// Round 16
// 313.592 us; speedup vs baseline: 1.0731x; 1.0020x over previous
//
#include <hip/hip_runtime.h>
#include <hip/hip_bf16.h>

// x:[1024,3,32,32] -> conv1(3->64)+relu -> conv2(64->128)+relu -> meanpool
// -> fc(128->256)+b -> *mask -> sage1(256->256)+relu -> sage2(256->128)
// Output [32,32,128] fp32.
//
// Workspace layout (<6MB):
//  [0,2M)        pooled4 [1024][4][128] f32 (band partials, pre-divide)
//  [2M,3M)       z1 [1024][256]
//  [3M,4M)       z2 [1024][256]
//  [4096K,+256K) l1T  [256][256] = s1lw^T
//  [4352K,+256K) w1pT [256][256] = (s1rw - s1lw/31)^T
//  [4608K,+128K) l2T  [256][128] = s2lw^T
//  [4736K,+128K) w2pT [256][128] = (s2rw - s2lw/31)^T
//  [4864K,+128K) fwT  [128][256] = fc_w^T
//  [4992K,+144K) w2b  [9][128][64] bf16 conv2 w, tap-major
//  [5136K,+4K)   w1b  [64][32] bf16 conv1 w+bias (k=27 slot = bias)

typedef __attribute__((ext_vector_type(8))) short bfrag;
typedef __attribute__((ext_vector_type(4))) float f32x4;
typedef __attribute__((ext_vector_type(16))) float f32x16;

static __device__ __forceinline__ unsigned short f2bf(float f) {
    union { float f; unsigned u; } v; v.f = f;
    unsigned r = v.u + 0x7fff + ((v.u >> 16) & 1);   // RNE (finite)
    return (unsigned short)(r >> 16);
}

// prep: grid 64. LDS-tiled transposes (coalesced both directions) + w2b/w1b repack.
__global__ __launch_bounds__(256) void prep_kernel(
    const float* __restrict__ s1lw, const float* __restrict__ s1rw,
    const float* __restrict__ s2lw, const float* __restrict__ s2rw,
    const float* __restrict__ c2w, const float* __restrict__ c1w,
    const float* __restrict__ c1b, const float* __restrict__ fcw,
    float* __restrict__ l1T, float* __restrict__ w1pT,
    float* __restrict__ l2T, float* __restrict__ w2pT,
    float* __restrict__ fwT,
    short* __restrict__ w2b, short* __restrict__ w1b) {
    const int blk = blockIdx.x, t = threadIdx.x;
    const int rr = t >> 6, cc = t & 63;
    const float inv31 = 1.f / 31.f;
    __shared__ float tA[64][65];
    __shared__ float tB[64][65];
    if (blk < 16) {                       // 256x256: [o][d] -> [d][o]
        int br = (blk >> 2) * 64, bc = (blk & 3) * 64;
#pragma unroll
        for (int i = 0; i < 16; ++i) {
            int o = br + i * 4 + rr;
            tA[i * 4 + rr][cc] = s1lw[o * 256 + bc + cc];
            tB[i * 4 + rr][cc] = s1rw[o * 256 + bc + cc];
        }
        __syncthreads();
#pragma unroll
        for (int i = 0; i < 16; ++i) {
            int d = bc + i * 4 + rr;
            float lw = tA[cc][i * 4 + rr];
            float rw = tB[cc][i * 4 + rr];
            l1T[d * 256 + br + cc]  = lw;
            w1pT[d * 256 + br + cc] = rw - lw * inv31;
        }
    } else if (blk < 24) {                // 128x256 -> 256x128
        int b = blk - 16;
        int br = (b >> 2) * 64, bc = (b & 3) * 64;
#pragma unroll
        for (int i = 0; i < 16; ++i) {
            int o = br + i * 4 + rr;
            tA[i * 4 + rr][cc] = s2lw[o * 256 + bc + cc];
            tB[i * 4 + rr][cc] = s2rw[o * 256 + bc + cc];
        }
        __syncthreads();
#pragma unroll
        for (int i = 0; i < 16; ++i) {
            int d = bc + i * 4 + rr;
            float lw = tA[cc][i * 4 + rr];
            float rw = tB[cc][i * 4 + rr];
            l2T[d * 128 + br + cc]  = lw;
            w2pT[d * 128 + br + cc] = rw - lw * inv31;
        }
    } else if (blk < 32) {                // fcw [256][128] -> fwT [128][256]
        int b = blk - 24;
        int br = (b >> 1) * 64, bc = (b & 1) * 64;
#pragma unroll
        for (int i = 0; i < 16; ++i) {
            int o = br + i * 4 + rr;
            tA[i * 4 + rr][cc] = fcw[o * 128 + bc + cc];
        }
        __syncthreads();
#pragma unroll
        for (int i = 0; i < 16; ++i) {
            int c = bc + i * 4 + rr;
            fwT[c * 256 + br + cc] = tA[cc][i * 4 + rr];
        }
    } else {                              // w2b[k][oc][ic] = c2w[oc][ic][k]
        int base = (blk - 32) * 2304 + t;
#pragma unroll
        for (int j = 0; j < 9; ++j) {
            int i = base + j * 256;
            int k = i >> 13, rem = i & 8191, oc = rem >> 6, ic = rem & 63;
            w2b[i] = (short)f2bf(c2w[(oc * 64 + ic) * 9 + k]);
        }
        if (blk == 32) {                  // w1b[oc][k], k=27 -> bias
            for (int j = t; j < 2048; j += 256) {
                int oc = j >> 5, k = j & 31;
                float v = (k < 27) ? c1w[oc * 27 + k] : (k == 27 ? c1b[oc] : 0.f);
                w1b[j] = (short)f2bf(v);
            }
        }
    }
}

// Fused conv1+conv2+pool: grid (4 bands of 8 rows, 1024 imgs).
// Phase A: conv1 via 16x16x32. Phase B: conv2 via 32x32x16 (r16: ~17% fewer
// matrix-pipe cycles than 16x16x32 at same FLOPs; 4 M=32 pos-tiles x 2 N=32
// oc-tiles, K=16 chunks). acc=128 AGPR, 2-stage B pipeline, (256,2) only
// (r8: tighter bound spills acc; r10: smaller tiles lose).
__global__ __launch_bounds__(256, 2) void fused_conv_kernel(
    const float* __restrict__ x, const short* __restrict__ w1b,
    const short* __restrict__ w2b, const float* __restrict__ b2,
    float* __restrict__ pooled4) {
    const int band = blockIdx.x, img = blockIdx.y;
    __shared__ short xt[3 * 12 * 34];     // 2448 B: input rows band*8-2..band*8+9
    __shared__ short c1t[10 * 34 * 72];   // 48960 B [row][col pad34][ic pad72]
    __shared__ float wsum[4][64];
    const int t = threadIdx.x;
    const int w = t >> 6, lane = t & 63;
    const int ln15 = lane & 15, q8 = (lane >> 4) * 8;
    const int ln31 = lane & 31, h8 = (lane >> 5) * 8;
    const int rg2 = w & 1, og = w >> 1;   // phase-B row-group / oc-group

    const float* xi = x + img * 3072;
    for (int idx = t; idx < 1224; idx += 256) {
        int c = idx / 408, rem = idx % 408, r = rem / 34, col = rem % 34;
        int y = band * 8 - 2 + r, xx = col - 1;
        float v = 0.f;
        if ((unsigned)y < 32u && (unsigned)xx < 32u) v = xi[c * 1024 + y * 32 + xx];
        xt[idx] = (short)f2bf(v);
    }
    {
        f32x4 z = {0.f, 0.f, 0.f, 0.f};
        for (int i = t; i < 180; i += 256) {          // 10r x 2c x 9 f32x4
            int r = i / 18, rem = i % 18, side = rem / 9, q = rem % 9;
            *(f32x4*)(c1t + (r * 34 + side * 33) * 72 + q * 8) = z;
        }
    }
    bfrag b1f[4];
#pragma unroll
    for (int ot = 0; ot < 4; ++ot)
        b1f[ot] = *(const bfrag*)(w1b + (ot * 16 + ln15) * 32 + q8);
    __syncthreads();

    // ---- phase A: conv1 -> c1t (16x16x32; 20 pos-tiles, wave w -> 5w..5w+4) ----
#pragma unroll 1
    for (int pt = 0; pt < 5; ++pt) {
        const int tile = w * 5 + pt;
        const int posA = tile * 16 + ln15;
        const int baseA = (posA >> 5) * 34 + (posA & 31);
        bfrag a1f;
#pragma unroll
        for (int j = 0; j < 8; ++j) {
            int k = q8 + j;
            int c = (k * 57) >> 9;               // k/9 for k<36
            int rem = k - 9 * c;
            int dy = (rem * 11) >> 5;            // rem/3 for rem<9
            int dx = rem - 3 * dy;
            int cc = c < 3 ? c : 2;
            short v = xt[cc * 408 + baseA + dy * 34 + dx];
            if (c >= 3) v = (k == 27) ? (short)0x3F80 : (short)0;
            a1f[j] = v;
        }
        f32x4 acc1[4];
#pragma unroll
        for (int ot = 0; ot < 4; ++ot) {
#pragma unroll
            for (int rg = 0; rg < 4; ++rg) acc1[ot][rg] = 0.f;
            acc1[ot] = __builtin_amdgcn_mfma_f32_16x16x32_bf16(
                a1f, b1f[ot], acc1[ot], 0, 0, 0);
        }
#pragma unroll
        for (int rg = 0; rg < 4; ++rg) {
            int pos = tile * 16 + (lane >> 4) * 4 + rg;  // 0..319
            int r = pos >> 5, xc = pos & 31;
            int y = band * 8 - 1 + r;
            bool valid = (unsigned)y < 32u;
#pragma unroll
            for (int ot = 0; ot < 4; ++ot) {
                float v = fmaxf(acc1[ot][rg], 0.f);
                c1t[(r * 34 + xc + 1) * 72 + ot * 16 + ln15] =
                    valid ? (short)f2bf(v) : (short)0;
            }
        }
    }
    __syncthreads();

    // ---- phase B: pipelined conv2 via 32x32x16 ----
    // A[m][k]: m=ln31 (pos col), k=h8+j (ic). B[k][n]: n=ln31 (oc), k=h8+j.
    // D: col(n=oc)=ln31, row(m=pos)=(reg&3)+8*(reg>>2)+4*(lane>>5).
    float b2v[2];
#pragma unroll
    for (int ot = 0; ot < 2; ++ot) b2v[ot] = b2[og * 64 + ot * 32 + ln31];

    f32x16 acc[4][2];
#pragma unroll
    for (int pt = 0; pt < 4; ++pt)
#pragma unroll
        for (int ot = 0; ot < 2; ++ot)
#pragma unroll
            for (int rg = 0; rg < 16; ++rg) acc[pt][ot][rg] = 0.f;

    int aBase[4];
#pragma unroll
    for (int pt = 0; pt < 4; ++pt) {
        int r = rg2 * 4 + pt;
        aBase[pt] = (r * 34 + ln31) * 72 + h8;
    }

    const short* wb0 = w2b + (og * 64 + ln31) * 64 + h8;
    auto loadB = [&](bfrag* dst, int tap) {
        const short* p = wb0 + tap * 8192;
#pragma unroll
        for (int kc = 0; kc < 4; ++kc)
#pragma unroll
            for (int ot = 0; ot < 2; ++ot)
                dst[kc * 2 + ot] = *(const bfrag*)(p + ot * 2048 + kc * 16);
    };
    auto compute = [&](const bfrag* bf, int tap) {
        const int dy = tap / 3, dx = tap - dy * 3;
        const int dOff = (dy * 34 + dx) * 72;          // wave-uniform -> SALU
#pragma unroll
        for (int pt = 0; pt < 4; ++pt) {
            const int a0 = aBase[pt] + dOff;
#pragma unroll
            for (int kc = 0; kc < 4; ++kc) {
                bfrag a2f = *(const bfrag*)(&c1t[a0 + kc * 16]);
#pragma unroll
                for (int ot = 0; ot < 2; ++ot)
                    acc[pt][ot] = __builtin_amdgcn_mfma_f32_32x32x16_bf16(
                        a2f, bf[kc * 2 + ot], acc[pt][ot], 0, 0, 0);
            }
        }
    };

    bfrag bA[8], bB[8];
    loadB(bA, 0);
#pragma unroll 1
    for (int tap = 0; tap < 9; tap += 2) {      // manual 2-stage pipeline
        if (tap + 1 < 9) loadB(bB, tap + 1);
        compute(bA, tap);
        if (tap + 2 < 9) loadB(bA, tap + 2);
        if (tap + 1 < 9) compute(bB, tap + 1);
    }

    // bias + relu + pool (wave covers 128 pos x 64 oc)
#pragma unroll
    for (int ot = 0; ot < 2; ++ot) {
        float s = 0.f;
#pragma unroll
        for (int pt = 0; pt < 4; ++pt)
#pragma unroll
            for (int rg = 0; rg < 16; ++rg)
                s += fmaxf(acc[pt][ot][rg] + b2v[ot], 0.f);
        s += __shfl_xor(s, 32, 64);              // combine the two m-halves
        if (lane < 32) wsum[w][ot * 32 + lane] = s;
    }
    __syncthreads();
    if (t < 128) {
        int og2 = t >> 6, oo = t & 63;
        pooled4[((size_t)img * 4 + band) * 128 + t] =
            wsum[og2 * 2][oo] + wsum[og2 * 2 + 1][oo];
    }
}

// fc: grid 1024 (one block per image) -- wide grid hides weight-load latency.
__global__ __launch_bounds__(256) void fc_kernel(
    const float* __restrict__ pooled4, const float* __restrict__ fwT,
    const float* __restrict__ fb, const float* __restrict__ mask,
    float* __restrict__ z1) {
    const int img = blockIdx.x;
    __shared__ float m[128];
    const int t = threadIdx.x;
    if (t < 128) {
        const float* p = pooled4 + (size_t)img * 4 * 128 + t;
        m[t] = (p[0] + p[128] + p[256] + p[384]) * (1.f / 1024.f);
    }
    __syncthreads();
    float acc = fb[t];
#pragma unroll 4
    for (int c = 0; c < 128; ++c) acc = fmaf(m[c], fwT[c * 256 + t], acc);  // coalesced
    z1[img * 256 + t] = acc * mask[img];
}

// sage1+relu: grid 256 = (bb, chunk of 4 nodes); thread t = output o.
__global__ __launch_bounds__(256) void sage1_kernel(
    const float* __restrict__ z1, const float* __restrict__ l1T,
    const float* __restrict__ lb, const float* __restrict__ w1pT,
    float* __restrict__ z2) {
    const int bb = blockIdx.x >> 3, chunk = blockIdx.x & 7;
    __shared__ float h[32 * 256];
    __shared__ float sl[256];
    const int t = threadIdx.x;
    const f32x4* zb4 = (const f32x4*)(z1 + bb * 8192);
    for (int idx = t; idx < 2048; idx += 256) ((f32x4*)h)[idx] = zb4[idx];
    __syncthreads();
    float s = 0.f;
#pragma unroll
    for (int n = 0; n < 32; ++n) s += h[n * 256 + t];
    sl[t] = s * (1.f / 31.f);
    __syncthreads();
    float c = lb[t];
#pragma unroll 4
    for (int d = 0; d < 256; ++d) c = fmaf(sl[d], l1T[d * 256 + t], c);
    float acc[4];
#pragma unroll
    for (int i = 0; i < 4; ++i) acc[i] = c;
    for (int d0 = 0; d0 < 256; d0 += 4) {
        float wv0 = w1pT[(d0 + 0) * 256 + t];
        float wv1 = w1pT[(d0 + 1) * 256 + t];
        float wv2 = w1pT[(d0 + 2) * 256 + t];
        float wv3 = w1pT[(d0 + 3) * 256 + t];
#pragma unroll
        for (int i = 0; i < 4; ++i) {
            f32x4 hv = *(const f32x4*)&h[(chunk * 4 + i) * 256 + d0];  // LDS broadcast
            acc[i] = fmaf(hv[0], wv0, acc[i]);
            acc[i] = fmaf(hv[1], wv1, acc[i]);
            acc[i] = fmaf(hv[2], wv2, acc[i]);
            acc[i] = fmaf(hv[3], wv3, acc[i]);
        }
    }
    for (int i = 0; i < 4; ++i)
        z2[(bb * 32 + chunk * 4 + i) * 256 + t] = fmaxf(acc[i], 0.f);
}

// sage2: grid 256 = (bb, chunk of 4 nodes); o = t&127, half = t>>7 (2 nodes each).
__global__ __launch_bounds__(256) void sage2_kernel(
    const float* __restrict__ z2, const float* __restrict__ l2T,
    const float* __restrict__ lb, const float* __restrict__ w2pT,
    float* __restrict__ out) {
    const int bb = blockIdx.x >> 3, chunk = blockIdx.x & 7;
    __shared__ float h[32 * 256];
    __shared__ float sl[256];
    const int t = threadIdx.x;
    const f32x4* zb4 = (const f32x4*)(z2 + bb * 8192);
    for (int idx = t; idx < 2048; idx += 256) ((f32x4*)h)[idx] = zb4[idx];
    __syncthreads();
    float s = 0.f;
#pragma unroll
    for (int n = 0; n < 32; ++n) s += h[n * 256 + t];
    sl[t] = s * (1.f / 31.f);
    __syncthreads();
    const int o = t & 127, half = t >> 7;
    float c = lb[o];
#pragma unroll 4
    for (int d = 0; d < 256; ++d) c = fmaf(sl[d], l2T[d * 128 + o], c);
    float acc[2];
    acc[0] = c; acc[1] = c;
    const int n0 = chunk * 4 + half * 2;
    for (int d0 = 0; d0 < 256; d0 += 4) {
        float wv0 = w2pT[(d0 + 0) * 128 + o];
        float wv1 = w2pT[(d0 + 1) * 128 + o];
        float wv2 = w2pT[(d0 + 2) * 128 + o];
        float wv3 = w2pT[(d0 + 3) * 128 + o];
#pragma unroll
        for (int ii = 0; ii < 2; ++ii) {
            f32x4 hv = *(const f32x4*)&h[(n0 + ii) * 256 + d0];
            acc[ii] = fmaf(hv[0], wv0, acc[ii]);
            acc[ii] = fmaf(hv[1], wv1, acc[ii]);
            acc[ii] = fmaf(hv[2], wv2, acc[ii]);
            acc[ii] = fmaf(hv[3], wv3, acc[ii]);
        }
    }
    for (int ii = 0; ii < 2; ++ii)
        out[(size_t)(bb * 32 + n0 + ii) * 128 + o] = acc[ii];
}

extern "C" void kernel_launch(void* const* d_in, const int* in_sizes, int n_in,
                              void* d_out, int out_size, void* d_ws, size_t ws_size,
                              hipStream_t stream) {
    const float* x    = (const float*)d_in[0];
    const float* mask = (const float*)d_in[1];
    const float* c1w  = (const float*)d_in[2];
    const float* c1b  = (const float*)d_in[3];
    const float* c2w  = (const float*)d_in[4];
    const float* c2b  = (const float*)d_in[5];
    const float* fcw  = (const float*)d_in[6];
    const float* fcb  = (const float*)d_in[7];
    const float* s1lw = (const float*)d_in[8];
    const float* s1lb = (const float*)d_in[9];
    const float* s1rw = (const float*)d_in[10];
    const float* s2lw = (const float*)d_in[11];
    const float* s2lb = (const float*)d_in[12];
    const float* s2rw = (const float*)d_in[13];
    float* out = (float*)d_out;

    char* ws = (char*)d_ws;
    float* pooled4 = (float*)(ws);
    float* z1      = (float*)(ws + 2048u * 1024);
    float* z2      = (float*)(ws + 3072u * 1024);
    float* l1T     = (float*)(ws + 4096u * 1024);
    float* w1pT    = (float*)(ws + 4352u * 1024);
    float* l2T     = (float*)(ws + 4608u * 1024);
    float* w2pT    = (float*)(ws + 4736u * 1024);
    float* fwT     = (float*)(ws + 4864u * 1024);
    short* w2b     = (short*)(ws + 4992u * 1024);
    short* w1b     = (short*)(ws + 5136u * 1024);

    prep_kernel<<<dim3(64), 256, 0, stream>>>(s1lw, s1rw, s2lw, s2rw, c2w, c1w, c1b,
                                              fcw, l1T, w1pT, l2T, w2pT, fwT, w2b, w1b);
    fused_conv_kernel<<<dim3(4, 1024), 256, 0, stream>>>(x, w1b, w2b, c2b, pooled4);
    fc_kernel<<<dim3(1024), 256, 0, stream>>>(pooled4, fwT, fcb, mask, z1);
    sage1_kernel<<<dim3(256), 256, 0, stream>>>(z1, l1T, s1lb, w1pT, z2);
    sage2_kernel<<<dim3(256), 256, 0, stream>>>(z2, l2T, s2lb, w2pT, out);
}

// Round 17
// 311.236 us; speedup vs baseline: 1.0812x; 1.0076x over previous
//
#include <hip/hip_runtime.h>
#include <hip/hip_bf16.h>

// x:[1024,3,32,32] -> conv1(3->64)+relu -> conv2(64->128)+relu -> meanpool
// -> fc(128->256)+b -> *mask -> sage1(256->256)+relu -> sage2(256->128)
// Output [32,32,128] fp32.
//
// Converged configuration (r17):
//  - fused conv1+conv2+pool, 16x16x32 MFMA, 128-acc wave tile, 2-stage B
//    pipeline, (256,2). Measured plateau ~193us; r8 (reg cap -> acc spill),
//    r10 (smaller tile -> lost B amortization), r16 (32x32 shape -> neutral)
//    all confirm latency-bound at 2 blocks/CU, not pipe-bound.
//  - split tail at wide grids (r14: merging regressed; gaps are <=10us).
//
// Workspace layout (<6MB):
//  [0,2M)        pooled4 [1024][4][128] f32 (band partials, pre-divide)
//  [2M,3M)       z1 [1024][256]
//  [3M,4M)       z2 [1024][256]
//  [4096K,+256K) l1T  [256][256] = s1lw^T
//  [4352K,+256K) w1pT [256][256] = (s1rw - s1lw/31)^T
//  [4608K,+128K) l2T  [256][128] = s2lw^T
//  [4736K,+128K) w2pT [256][128] = (s2rw - s2lw/31)^T
//  [4864K,+128K) fwT  [128][256] = fc_w^T
//  [4992K,+144K) w2b  [9][128][64] bf16 conv2 w, tap-major
//  [5136K,+4K)   w1b  [64][32] bf16 conv1 w+bias (k=27 slot = bias)

typedef __attribute__((ext_vector_type(8))) short bfrag;
typedef __attribute__((ext_vector_type(4))) float f32x4;

static __device__ __forceinline__ unsigned short f2bf(float f) {
    union { float f; unsigned u; } v; v.f = f;
    unsigned r = v.u + 0x7fff + ((v.u >> 16) & 1);   // RNE (finite)
    return (unsigned short)(r >> 16);
}

// prep: grid 64. LDS-tiled transposes (coalesced both directions) + w2b/w1b repack.
__global__ __launch_bounds__(256) void prep_kernel(
    const float* __restrict__ s1lw, const float* __restrict__ s1rw,
    const float* __restrict__ s2lw, const float* __restrict__ s2rw,
    const float* __restrict__ c2w, const float* __restrict__ c1w,
    const float* __restrict__ c1b, const float* __restrict__ fcw,
    float* __restrict__ l1T, float* __restrict__ w1pT,
    float* __restrict__ l2T, float* __restrict__ w2pT,
    float* __restrict__ fwT,
    short* __restrict__ w2b, short* __restrict__ w1b) {
    const int blk = blockIdx.x, t = threadIdx.x;
    const int rr = t >> 6, cc = t & 63;
    const float inv31 = 1.f / 31.f;
    __shared__ float tA[64][65];
    __shared__ float tB[64][65];
    if (blk < 16) {                       // 256x256: [o][d] -> [d][o]
        int br = (blk >> 2) * 64, bc = (blk & 3) * 64;
#pragma unroll
        for (int i = 0; i < 16; ++i) {
            int o = br + i * 4 + rr;
            tA[i * 4 + rr][cc] = s1lw[o * 256 + bc + cc];
            tB[i * 4 + rr][cc] = s1rw[o * 256 + bc + cc];
        }
        __syncthreads();
#pragma unroll
        for (int i = 0; i < 16; ++i) {
            int d = bc + i * 4 + rr;
            float lw = tA[cc][i * 4 + rr];
            float rw = tB[cc][i * 4 + rr];
            l1T[d * 256 + br + cc]  = lw;
            w1pT[d * 256 + br + cc] = rw - lw * inv31;
        }
    } else if (blk < 24) {                // 128x256 -> 256x128
        int b = blk - 16;
        int br = (b >> 2) * 64, bc = (b & 3) * 64;
#pragma unroll
        for (int i = 0; i < 16; ++i) {
            int o = br + i * 4 + rr;
            tA[i * 4 + rr][cc] = s2lw[o * 256 + bc + cc];
            tB[i * 4 + rr][cc] = s2rw[o * 256 + bc + cc];
        }
        __syncthreads();
#pragma unroll
        for (int i = 0; i < 16; ++i) {
            int d = bc + i * 4 + rr;
            float lw = tA[cc][i * 4 + rr];
            float rw = tB[cc][i * 4 + rr];
            l2T[d * 128 + br + cc]  = lw;
            w2pT[d * 128 + br + cc] = rw - lw * inv31;
        }
    } else if (blk < 32) {                // fcw [256][128] -> fwT [128][256]
        int b = blk - 24;
        int br = (b >> 1) * 64, bc = (b & 1) * 64;
#pragma unroll
        for (int i = 0; i < 16; ++i) {
            int o = br + i * 4 + rr;
            tA[i * 4 + rr][cc] = fcw[o * 128 + bc + cc];
        }
        __syncthreads();
#pragma unroll
        for (int i = 0; i < 16; ++i) {
            int c = bc + i * 4 + rr;
            fwT[c * 256 + br + cc] = tA[cc][i * 4 + rr];
        }
    } else {                              // w2b[k][oc][ic] = c2w[oc][ic][k]
        int base = (blk - 32) * 2304 + t;
#pragma unroll
        for (int j = 0; j < 9; ++j) {
            int i = base + j * 256;
            int k = i >> 13, rem = i & 8191, oc = rem >> 6, ic = rem & 63;
            w2b[i] = (short)f2bf(c2w[(oc * 64 + ic) * 9 + k]);
        }
        if (blk == 32) {                  // w1b[oc][k], k=27 -> bias
            for (int j = t; j < 2048; j += 256) {
                int oc = j >> 5, k = j & 31;
                float v = (k < 27) ? c1w[oc * 27 + k] : (k == 27 ? c1b[oc] : 0.f);
                w1b[j] = (short)f2bf(v);
            }
        }
    }
}

// Fused conv1+conv2+pool: grid (4 bands of 8 rows, 1024 imgs).
__global__ __launch_bounds__(256, 2) void fused_conv_kernel(
    const float* __restrict__ x, const short* __restrict__ w1b,
    const short* __restrict__ w2b, const float* __restrict__ b2,
    float* __restrict__ pooled4) {
    const int band = blockIdx.x, img = blockIdx.y;
    __shared__ short xt[3 * 12 * 34];     // 2448 B: input rows band*8-2..band*8+9
    __shared__ short c1t[10 * 34 * 72];   // 48960 B [row][col pad34][ic pad72]
    __shared__ float wsum[4][64];
    const int t = threadIdx.x;
    const int w = t >> 6, lane = t & 63;
    const int ln15 = lane & 15, q8 = (lane >> 4) * 8;
    const int rg2 = w & 1, og = w >> 1;   // phase-B row-group / oc-group

    const float* xi = x + img * 3072;
    for (int idx = t; idx < 1224; idx += 256) {
        int c = idx / 408, rem = idx % 408, r = rem / 34, col = rem % 34;
        int y = band * 8 - 2 + r, xx = col - 1;
        float v = 0.f;
        if ((unsigned)y < 32u && (unsigned)xx < 32u) v = xi[c * 1024 + y * 32 + xx];
        xt[idx] = (short)f2bf(v);
    }
    {
        f32x4 z = {0.f, 0.f, 0.f, 0.f};
        for (int i = t; i < 180; i += 256) {          // 10r x 2c x 9 f32x4
            int r = i / 18, rem = i % 18, side = rem / 9, q = rem % 9;
            *(f32x4*)(c1t + (r * 34 + side * 33) * 72 + q * 8) = z;
        }
    }
    bfrag b1f[4];
#pragma unroll
    for (int ot = 0; ot < 4; ++ot)
        b1f[ot] = *(const bfrag*)(w1b + (ot * 16 + ln15) * 32 + q8);
    __syncthreads();

    // ---- phase A: conv1 -> c1t (16x16x32; 20 pos-tiles, wave w -> 5w..5w+4) ----
#pragma unroll 1
    for (int pt = 0; pt < 5; ++pt) {
        const int tile = w * 5 + pt;
        const int posA = tile * 16 + ln15;
        const int baseA = (posA >> 5) * 34 + (posA & 31);
        bfrag a1f;
#pragma unroll
        for (int j = 0; j < 8; ++j) {
            int k = q8 + j;
            int c = (k * 57) >> 9;               // k/9 for k<36
            int rem = k - 9 * c;
            int dy = (rem * 11) >> 5;            // rem/3 for rem<9
            int dx = rem - 3 * dy;
            int cc = c < 3 ? c : 2;
            short v = xt[cc * 408 + baseA + dy * 34 + dx];
            if (c >= 3) v = (k == 27) ? (short)0x3F80 : (short)0;
            a1f[j] = v;
        }
        f32x4 acc1[4];
#pragma unroll
        for (int ot = 0; ot < 4; ++ot) {
#pragma unroll
            for (int rg = 0; rg < 4; ++rg) acc1[ot][rg] = 0.f;
            acc1[ot] = __builtin_amdgcn_mfma_f32_16x16x32_bf16(
                a1f, b1f[ot], acc1[ot], 0, 0, 0);
        }
#pragma unroll
        for (int rg = 0; rg < 4; ++rg) {
            int pos = tile * 16 + (lane >> 4) * 4 + rg;  // 0..319
            int r = pos >> 5, xc = pos & 31;
            int y = band * 8 - 1 + r;
            bool valid = (unsigned)y < 32u;
#pragma unroll
            for (int ot = 0; ot < 4; ++ot) {
                float v = fmaxf(acc1[ot][rg], 0.f);
                c1t[(r * 34 + xc + 1) * 72 + ot * 16 + ln15] =
                    valid ? (short)f2bf(v) : (short)0;
            }
        }
    }
    __syncthreads();

    // ---- phase B: pipelined conv2 (16x16x32, the measured-best shape) ----
    float b2v[4];
#pragma unroll
    for (int ot = 0; ot < 4; ++ot) b2v[ot] = b2[og * 64 + ot * 16 + ln15];

    f32x4 acc[8][4];
#pragma unroll
    for (int pt = 0; pt < 8; ++pt)
#pragma unroll
        for (int ot = 0; ot < 4; ++ot)
#pragma unroll
            for (int rg = 0; rg < 4; ++rg) acc[pt][ot][rg] = 0.f;

    int aBase[8];
#pragma unroll
    for (int pt = 0; pt < 8; ++pt) {
        int r = rg2 * 4 + (pt >> 1);
        int xc = ((pt & 1) << 4) + ln15;
        aBase[pt] = (r * 34 + xc) * 72 + q8;
    }

    const short* wb0 = w2b + (og * 64 + ln15) * 64 + q8;
    auto loadB = [&](bfrag* dst, int tap) {
        const short* p = wb0 + tap * 8192;
#pragma unroll
        for (int kc = 0; kc < 2; ++kc)
#pragma unroll
            for (int ot = 0; ot < 4; ++ot)
                dst[kc * 4 + ot] = *(const bfrag*)(p + ot * 1024 + kc * 32);
    };
    auto compute = [&](const bfrag* bf, int tap) {
        const int dy = tap / 3, dx = tap - dy * 3;
        const int dOff = (dy * 34 + dx) * 72;          // wave-uniform -> SALU
#pragma unroll
        for (int pt = 0; pt < 8; ++pt) {
            const int a0 = aBase[pt] + dOff;
#pragma unroll
            for (int kc = 0; kc < 2; ++kc) {
                bfrag a2f = *(const bfrag*)(&c1t[a0 + kc * 32]);
#pragma unroll
                for (int ot = 0; ot < 4; ++ot)
                    acc[pt][ot] = __builtin_amdgcn_mfma_f32_16x16x32_bf16(
                        a2f, bf[kc * 4 + ot], acc[pt][ot], 0, 0, 0);
            }
        }
    };

    bfrag bA[8], bB[8];
    loadB(bA, 0);
#pragma unroll 1
    for (int tap = 0; tap < 9; tap += 2) {      // manual 2-stage pipeline
        if (tap + 1 < 9) loadB(bB, tap + 1);
        compute(bA, tap);
        if (tap + 2 < 9) loadB(bA, tap + 2);
        if (tap + 1 < 9) compute(bB, tap + 1);
    }

#pragma unroll
    for (int ot = 0; ot < 4; ++ot) {
        float s = 0.f;
#pragma unroll
        for (int pt = 0; pt < 8; ++pt)
#pragma unroll
            for (int rg = 0; rg < 4; ++rg)
                s += fmaxf(acc[pt][ot][rg] + b2v[ot], 0.f);
        s += __shfl_xor(s, 16, 64);
        s += __shfl_xor(s, 32, 64);
        if (lane < 16) wsum[w][ot * 16 + ln15] = s;
    }
    __syncthreads();
    if (t < 128) {
        int og2 = t >> 6, oo = t & 63;
        pooled4[((size_t)img * 4 + band) * 128 + t] =
            wsum[og2 * 2][oo] + wsum[og2 * 2 + 1][oo];
    }
}

// fc: grid 1024 (one block per image) -- wide grid hides weight-load latency.
__global__ __launch_bounds__(256) void fc_kernel(
    const float* __restrict__ pooled4, const float* __restrict__ fwT,
    const float* __restrict__ fb, const float* __restrict__ mask,
    float* __restrict__ z1) {
    const int img = blockIdx.x;
    __shared__ float m[128];
    const int t = threadIdx.x;
    if (t < 128) {
        const float* p = pooled4 + (size_t)img * 4 * 128 + t;
        m[t] = (p[0] + p[128] + p[256] + p[384]) * (1.f / 1024.f);
    }
    __syncthreads();
    float acc = fb[t];
#pragma unroll 4
    for (int c = 0; c < 128; ++c) acc = fmaf(m[c], fwT[c * 256 + t], acc);  // coalesced
    z1[img * 256 + t] = acc * mask[img];
}

// sage1+relu: grid 256 = (bb, chunk of 4 nodes); thread t = output o.
__global__ __launch_bounds__(256) void sage1_kernel(
    const float* __restrict__ z1, const float* __restrict__ l1T,
    const float* __restrict__ lb, const float* __restrict__ w1pT,
    float* __restrict__ z2) {
    const int bb = blockIdx.x >> 3, chunk = blockIdx.x & 7;
    __shared__ float h[32 * 256];
    __shared__ float sl[256];
    const int t = threadIdx.x;
    const f32x4* zb4 = (const f32x4*)(z1 + bb * 8192);
    for (int idx = t; idx < 2048; idx += 256) ((f32x4*)h)[idx] = zb4[idx];
    __syncthreads();
    float s = 0.f;
#pragma unroll
    for (int n = 0; n < 32; ++n) s += h[n * 256 + t];
    sl[t] = s * (1.f / 31.f);
    __syncthreads();
    float c = lb[t];
#pragma unroll 4
    for (int d = 0; d < 256; ++d) c = fmaf(sl[d], l1T[d * 256 + t], c);
    float acc[4];
#pragma unroll
    for (int i = 0; i < 4; ++i) acc[i] = c;
    for (int d0 = 0; d0 < 256; d0 += 4) {
        float wv0 = w1pT[(d0 + 0) * 256 + t];
        float wv1 = w1pT[(d0 + 1) * 256 + t];
        float wv2 = w1pT[(d0 + 2) * 256 + t];
        float wv3 = w1pT[(d0 + 3) * 256 + t];
#pragma unroll
        for (int i = 0; i < 4; ++i) {
            f32x4 hv = *(const f32x4*)&h[(chunk * 4 + i) * 256 + d0];  // LDS broadcast
            acc[i] = fmaf(hv[0], wv0, acc[i]);
            acc[i] = fmaf(hv[1], wv1, acc[i]);
            acc[i] = fmaf(hv[2], wv2, acc[i]);
            acc[i] = fmaf(hv[3], wv3, acc[i]);
        }
    }
    for (int i = 0; i < 4; ++i)
        z2[(bb * 32 + chunk * 4 + i) * 256 + t] = fmaxf(acc[i], 0.f);
}

// sage2: grid 256 = (bb, chunk of 4 nodes); o = t&127, half = t>>7 (2 nodes each).
__global__ __launch_bounds__(256) void sage2_kernel(
    const float* __restrict__ z2, const float* __restrict__ l2T,
    const float* __restrict__ lb, const float* __restrict__ w2pT,
    float* __restrict__ out) {
    const int bb = blockIdx.x >> 3, chunk = blockIdx.x & 7;
    __shared__ float h[32 * 256];
    __shared__ float sl[256];
    const int t = threadIdx.x;
    const f32x4* zb4 = (const f32x4*)(z2 + bb * 8192);
    for (int idx = t; idx < 2048; idx += 256) ((f32x4*)h)[idx] = zb4[idx];
    __syncthreads();
    float s = 0.f;
#pragma unroll
    for (int n = 0; n < 32; ++n) s += h[n * 256 + t];
    sl[t] = s * (1.f / 31.f);
    __syncthreads();
    const int o = t & 127, half = t >> 7;
    float c = lb[o];
#pragma unroll 4
    for (int d = 0; d < 256; ++d) c = fmaf(sl[d], l2T[d * 128 + o], c);
    float acc[2];
    acc[0] = c; acc[1] = c;
    const int n0 = chunk * 4 + half * 2;
    for (int d0 = 0; d0 < 256; d0 += 4) {
        float wv0 = w2pT[(d0 + 0) * 128 + o];
        float wv1 = w2pT[(d0 + 1) * 128 + o];
        float wv2 = w2pT[(d0 + 2) * 128 + o];
        float wv3 = w2pT[(d0 + 3) * 128 + o];
#pragma unroll
        for (int ii = 0; ii < 2; ++ii) {
            f32x4 hv = *(const f32x4*)&h[(n0 + ii) * 256 + d0];
            acc[ii] = fmaf(hv[0], wv0, acc[ii]);
            acc[ii] = fmaf(hv[1], wv1, acc[ii]);
            acc[ii] = fmaf(hv[2], wv2, acc[ii]);
            acc[ii] = fmaf(hv[3], wv3, acc[ii]);
        }
    }
    for (int ii = 0; ii < 2; ++ii)
        out[(size_t)(bb * 32 + n0 + ii) * 128 + o] = acc[ii];
}

extern "C" void kernel_launch(void* const* d_in, const int* in_sizes, int n_in,
                              void* d_out, int out_size, void* d_ws, size_t ws_size,
                              hipStream_t stream) {
    const float* x    = (const float*)d_in[0];
    const float* mask = (const float*)d_in[1];
    const float* c1w  = (const float*)d_in[2];
    const float* c1b  = (const float*)d_in[3];
    const float* c2w  = (const float*)d_in[4];
    const float* c2b  = (const float*)d_in[5];
    const float* fcw  = (const float*)d_in[6];
    const float* fcb  = (const float*)d_in[7];
    const float* s1lw = (const float*)d_in[8];
    const float* s1lb = (const float*)d_in[9];
    const float* s1rw = (const float*)d_in[10];
    const float* s2lw = (const float*)d_in[11];
    const float* s2lb = (const float*)d_in[12];
    const float* s2rw = (const float*)d_in[13];
    float* out = (float*)d_out;

    char* ws = (char*)d_ws;
    float* pooled4 = (float*)(ws);
    float* z1      = (float*)(ws + 2048u * 1024);
    float* z2      = (float*)(ws + 3072u * 1024);
    float* l1T     = (float*)(ws + 4096u * 1024);
    float* w1pT    = (float*)(ws + 4352u * 1024);
    float* l2T     = (float*)(ws + 4608u * 1024);
    float* w2pT    = (float*)(ws + 4736u * 1024);
    float* fwT     = (float*)(ws + 4864u * 1024);
    short* w2b     = (short*)(ws + 4992u * 1024);
    short* w1b     = (short*)(ws + 5136u * 1024);

    prep_kernel<<<dim3(64), 256, 0, stream>>>(s1lw, s1rw, s2lw, s2rw, c2w, c1w, c1b,
                                              fcw, l1T, w1pT, l2T, w2pT, fwT, w2b, w1b);
    fused_conv_kernel<<<dim3(4, 1024), 256, 0, stream>>>(x, w1b, w2b, c2b, pooled4);
    fc_kernel<<<dim3(1024), 256, 0, stream>>>(pooled4, fwT, fcb, mask, z1);
    sage1_kernel<<<dim3(256), 256, 0, stream>>>(z1, l1T, s1lb, w1pT, z2);
    sage2_kernel<<<dim3(256), 256, 0, stream>>>(z2, l2T, s2lb, w2pT, out);
}